// Round 5
// baseline (417.209 us; speedup 1.0000x reference)
//
#include <hip/hip_runtime.h>

#define N_NODES 30000
#define N_EDGES 480000
#define ETOT    510000   // edges + self loops
#define F_IN    512
#define WIDTH   256
#define NCLS    40
#define KCAT    768      // WIDTH*3
#define NPAD    48       // NCLS padded to 3 MFMA col-tiles

typedef __attribute__((ext_vector_type(8))) short short8;
typedef __attribute__((ext_vector_type(4))) float f32x4;

__device__ __forceinline__ unsigned short f2bf(float f){
  unsigned u = __float_as_uint(f);
  u += 0x7fffu + ((u >> 16) & 1u);   // RTNE
  return (unsigned short)(u >> 16);
}
__device__ __forceinline__ float b2f(unsigned short s){
  return __uint_as_float(((unsigned)s) << 16);
}

// ---------------- transpose W [K][Nc] f32 -> Wt [Nc][K] bf16 ----------------
__global__ void transpose_w_kernel(const float* __restrict__ W, unsigned short* __restrict__ Wt,
                                   int K, int Nc){
  int k = blockIdx.x * blockDim.x + threadIdx.x;
  int n = blockIdx.y;
  if (k < K) Wt[(size_t)n * K + k] = f2bf(W[(size_t)k * Nc + n]);
}

// ---------------- transpose+pad Wo [768][40] f32 -> WoT [48][768] bf16 ----------------
__global__ void transpose_wo_kernel(const float* __restrict__ Wo, unsigned short* __restrict__ WoT){
  int i = blockIdx.x * blockDim.x + threadIdx.x;   // i < 48*768
  if (i < NPAD * KCAT){
    int c = i / KCAT, k = i - c * KCAT;
    WoT[i] = (c < NCLS) ? f2bf(Wo[(size_t)k * NCLS + c]) : (unsigned short)0;
  }
}

// ---------------- CSR build ----------------
__global__ void zero_kernel(int* __restrict__ p, int n){
  int i = blockIdx.x * blockDim.x + threadIdx.x;
  if (i < n) p[i] = 0;
}

__global__ void hist_kernel(const int* __restrict__ ei, int* __restrict__ counts){
  int e = blockIdx.x * blockDim.x + threadIdx.x;
  if (e < ETOT){
    int d = (e < N_EDGES) ? ei[N_EDGES + e] : (e - N_EDGES);
    atomicAdd(&counts[d], 1);
  }
}

__global__ __launch_bounds__(1024) void scan_kernel(const int* __restrict__ counts,
                                                    int* __restrict__ offsets,
                                                    int* __restrict__ cursor, int n){
  __shared__ int wsum[16];
  int tid = threadIdx.x, lane = tid & 63, wid = tid >> 6;
  int running = 0;
  int nchunks = (n + 1023) >> 10;
  for (int ch = 0; ch < nchunks; ++ch){
    int i = (ch << 10) + tid;
    int v = (i < n) ? counts[i] : 0;
    int x = v;
    #pragma unroll
    for (int off = 1; off < 64; off <<= 1){
      int t = __shfl_up(x, off, 64);
      if (lane >= off) x += t;
    }
    if (lane == 63) wsum[wid] = x;
    __syncthreads();
    if (wid == 0){
      int s = (lane < 16) ? wsum[lane] : 0;
      #pragma unroll
      for (int off = 1; off < 16; off <<= 1){
        int t = __shfl_up(s, off, 64);
        if (lane >= off) s += t;
      }
      if (lane < 16) wsum[lane] = s;
    }
    __syncthreads();
    int waveprefix = (wid > 0) ? wsum[wid - 1] : 0;
    int excl = x - v + waveprefix + running;
    if (i < n){ offsets[i] = excl; cursor[i] = excl; }
    running += wsum[15];
    __syncthreads();
  }
  if (tid == 0) offsets[n] = running;
}

__global__ void scatter_kernel(const int* __restrict__ ei, int* __restrict__ cursor,
                               int* __restrict__ srcs){
  int e = blockIdx.x * blockDim.x + threadIdx.x;
  if (e < ETOT){
    int s, d;
    if (e < N_EDGES){ s = ei[e]; d = ei[N_EDGES + e]; }
    else { s = e - N_EDGES; d = s; }
    int pos = atomicAdd(&cursor[d], 1);
    srcs[pos] = s;
  }
}

// ---------------- fused GEMM + es/ed + bf16-h epilogue (v2) ----------------
// 4 waves; wave w owns rows 0..63 x cols 64w..64w+63 (4x4 tiles of 16x16x32).
// LDS granule-transposed (chunk-major): slot = chunk*rows + row, granule = 16B.
// -> staging writes bank = tid*4 % 32 (2-way, free); frag reads bank = l15*4 % 32 (2-way, free).
// Per K-32 iter per wave: 8 ds_read_b128 : 16 MFMA (m93 ratio).
// Head h == wave h's col range, so es/ed reduction is wave-local.
#define BM 64
#define BK 32

template<bool AF32>
__global__ __launch_bounds__(256) void gemm_fused_kernel(const void* __restrict__ Araw,
                                                         const unsigned short* __restrict__ Bt,
                                                         const float* __restrict__ a_s,
                                                         const float* __restrict__ a_d,
                                                         float* __restrict__ es,
                                                         float* __restrict__ ed,
                                                         unsigned short* __restrict__ hb,
                                                         int M, int K){
  __shared__ unsigned short Als[4 * 64 * 8];    // slot = c*64 + r   (4 KB)
  __shared__ unsigned short Bls[4 * 256 * 8];   // slot = c*256 + n  (16 KB)
  int tid = threadIdx.x;
  int lane = tid & 63, wid = tid >> 6;
  int l15 = lane & 15, quad = lane >> 4;
  int m0 = blockIdx.x * BM;

  f32x4 acc[4][4];   // [rt][ct]
  #pragma unroll
  for (int rt = 0; rt < 4; ++rt)
    #pragma unroll
    for (int ct = 0; ct < 4; ++ct) acc[rt][ct] = (f32x4){0.f, 0.f, 0.f, 0.f};

  // staging assignment: A granule (row ar, chunk ac); B col tid, chunks 0..3
  int ar = tid & 63, ac = tid >> 6;
  int agrow = m0 + ar; if (agrow >= M) agrow = M - 1;

  for (int k0 = 0; k0 < K; k0 += BK){
    __syncthreads();
    if (AF32){
      const float* Af = (const float*)Araw + (size_t)agrow * K + k0 + 8 * ac;
      float4 v0 = *(const float4*)(Af);
      float4 v1 = *(const float4*)(Af + 4);
      ushort4 p0 = {f2bf(v0.x), f2bf(v0.y), f2bf(v0.z), f2bf(v0.w)};
      ushort4 p1 = {f2bf(v1.x), f2bf(v1.y), f2bf(v1.z), f2bf(v1.w)};
      *(ushort4*)(&Als[(ac * 64 + ar) * 8])     = p0;
      *(ushort4*)(&Als[(ac * 64 + ar) * 8 + 4]) = p1;
    } else {
      const unsigned short* Ab = (const unsigned short*)Araw;
      uint4 av = *(const uint4*)(Ab + (size_t)agrow * K + k0 + 8 * ac);
      *(uint4*)(&Als[(ac * 64 + ar) * 8]) = av;
    }
    {
      const unsigned short* src = Bt + (size_t)tid * K + k0;
      uint4 b0 = *(const uint4*)(src);
      uint4 b1 = *(const uint4*)(src + 8);
      uint4 b2 = *(const uint4*)(src + 16);
      uint4 b3 = *(const uint4*)(src + 24);
      *(uint4*)(&Bls[(0 * 256 + tid) * 8]) = b0;
      *(uint4*)(&Bls[(1 * 256 + tid) * 8]) = b1;
      *(uint4*)(&Bls[(2 * 256 + tid) * 8]) = b2;
      *(uint4*)(&Bls[(3 * 256 + tid) * 8]) = b3;
    }
    __syncthreads();
    short8 af[4], bf[4];
    #pragma unroll
    for (int rt = 0; rt < 4; ++rt)
      af[rt] = *(const short8*)(&Als[(quad * 64 + rt * 16 + l15) * 8]);
    #pragma unroll
    for (int ct = 0; ct < 4; ++ct)
      bf[ct] = *(const short8*)(&Bls[(quad * 256 + wid * 64 + ct * 16 + l15) * 8]);
    #pragma unroll
    for (int rt = 0; rt < 4; ++rt)
      #pragma unroll
      for (int ct = 0; ct < 4; ++ct)
        acc[rt][ct] = __builtin_amdgcn_mfma_f32_16x16x32_bf16(af[rt], bf[ct], acc[rt][ct], 0, 0, 0);
  }

  int colbase = wid * 64;

  // h store: pair adjacent cols (l15 even packs own + l15+1) -> 4B stores, 32B segments
  #pragma unroll
  for (int rt = 0; rt < 4; ++rt){
    int row0 = m0 + rt * 16 + quad * 4;
    #pragma unroll
    for (int i = 0; i < 4; ++i){
      int grow = row0 + i;
      unsigned vo[4];
      #pragma unroll
      for (int ct = 0; ct < 4; ++ct){
        unsigned lo = (unsigned)f2bf(acc[rt][ct][i]);
        unsigned hi = (unsigned)__shfl_xor((int)lo, 1, 64);
        vo[ct] = lo | (hi << 16);
      }
      if ((l15 & 1) == 0 && grow < M){
        unsigned short* hrow = hb + (size_t)grow * WIDTH + colbase + l15;
        *(unsigned*)(hrow)      = vo[0];
        *(unsigned*)(hrow + 16) = vo[1];
        *(unsigned*)(hrow + 32) = vo[2];
        *(unsigned*)(hrow + 48) = vo[3];
      }
    }
  }

  // es/ed: head == wid; dot over this wave's 64 cols, reduce over 16 l15-lanes
  float asv[4], adv[4];
  #pragma unroll
  for (int ct = 0; ct < 4; ++ct){
    asv[ct] = a_s[wid * 64 + ct * 16 + l15];
    adv[ct] = a_d[wid * 64 + ct * 16 + l15];
  }
  #pragma unroll
  for (int rt = 0; rt < 4; ++rt){
    int row0 = m0 + rt * 16 + quad * 4;
    #pragma unroll
    for (int i = 0; i < 4; ++i){
      float se = acc[rt][0][i] * asv[0] + acc[rt][1][i] * asv[1]
               + acc[rt][2][i] * asv[2] + acc[rt][3][i] * asv[3];
      float sd = acc[rt][0][i] * adv[0] + acc[rt][1][i] * adv[1]
               + acc[rt][2][i] * adv[2] + acc[rt][3][i] * adv[3];
      #pragma unroll
      for (int off = 1; off < 16; off <<= 1){
        se += __shfl_xor(se, off, 64);
        sd += __shfl_xor(sd, off, 64);
      }
      int grow = row0 + i;
      if (l15 == 0 && grow < M){
        es[grow * 4 + wid] = se;
        ed[grow * 4 + wid] = sd;
      }
    }
  }
}

// ---------------- aggregation: one node per HALF-wave ----------------
__global__ __launch_bounds__(256) void agg_kernel(const int* __restrict__ offsets,
                                                  const int* __restrict__ srcs,
                                                  const float* __restrict__ es,
                                                  const float* __restrict__ ed,
                                                  const unsigned short* __restrict__ hb,
                                                  const float* __restrict__ bias,
                                                  unsigned short* __restrict__ hout){
  __shared__ float eLds[8][64][4];
  __shared__ int   sLds[8][64];
  int wid = threadIdx.x >> 6;
  int lane = threadIdx.x & 63;
  int half = lane >> 5, l32 = lane & 31;
  int slot = wid * 2 + half;
  int n = blockIdx.x * 8 + slot;
  int base = offsets[n];
  int deg = offsets[n + 1] - base;
  float4 edv = *(const float4*)(ed + n * 4);

  float m0 = -1e30f, m1 = -1e30f, m2 = -1e30f, m3 = -1e30f;
  for (int i = l32; i < deg; i += 32){
    int s = srcs[base + i];
    float4 ev = *(const float4*)(es + s * 4);
    float e0 = ev.x + edv.x, e1 = ev.y + edv.y, e2 = ev.z + edv.z, e3 = ev.w + edv.w;
    e0 = e0 > 0.f ? e0 : 0.2f * e0;
    e1 = e1 > 0.f ? e1 : 0.2f * e1;
    e2 = e2 > 0.f ? e2 : 0.2f * e2;
    e3 = e3 > 0.f ? e3 : 0.2f * e3;
    if (i < 64){
      sLds[slot][i] = s;
      *(float4*)(&eLds[slot][i][0]) = (float4){e0, e1, e2, e3};
    }
    m0 = fmaxf(m0, e0); m1 = fmaxf(m1, e1); m2 = fmaxf(m2, e2); m3 = fmaxf(m3, e3);
  }
  #pragma unroll
  for (int off = 1; off < 32; off <<= 1){
    m0 = fmaxf(m0, __shfl_xor(m0, off, 64));
    m1 = fmaxf(m1, __shfl_xor(m1, off, 64));
    m2 = fmaxf(m2, __shfl_xor(m2, off, 64));
    m3 = fmaxf(m3, __shfl_xor(m3, off, 64));
  }
  int head = l32 >> 3;
  float mh  = (head == 0) ? m0 : (head == 1) ? m1 : (head == 2) ? m2 : m3;
  float edh = (head == 0) ? edv.x : (head == 1) ? edv.y : (head == 2) ? edv.z : edv.w;

  float2 a0 = {0.f,0.f}, a1 = {0.f,0.f}, a2 = {0.f,0.f}, a3 = {0.f,0.f};
  float den = 0.f;
  const unsigned short* hcol = hb + 8 * l32;
  for (int i = 0; i < deg; i += 8){
    int sidx[8]; float w[8];
    #pragma unroll
    for (int u = 0; u < 8; ++u){
      int idx = i + u;
      bool v = idx < deg;
      float le; int s;
      if (idx < 64 || !v){
        int ic = v ? idx : 0;
        if (ic >= 64) ic = 0;
        s  = sLds[slot][ic];
        le = eLds[slot][ic][head];
      } else {
        s = srcs[base + idx];
        float e = es[s * 4 + head] + edh;
        le = e > 0.f ? e : 0.2f * e;
      }
      sidx[u] = s;
      w[u] = v ? __expf(le - mh) : 0.f;
    }
    uint4 hv[8];
    #pragma unroll
    for (int u = 0; u < 8; ++u)
      hv[u] = *(const uint4*)(hcol + (size_t)sidx[u] * WIDTH);
    #pragma unroll
    for (int u = 0; u < 8; ++u){
      float wu = w[u];
      den += wu;
      a0.x += wu * __uint_as_float(hv[u].x << 16);
      a0.y += wu * __uint_as_float(hv[u].x & 0xffff0000u);
      a1.x += wu * __uint_as_float(hv[u].y << 16);
      a1.y += wu * __uint_as_float(hv[u].y & 0xffff0000u);
      a2.x += wu * __uint_as_float(hv[u].z << 16);
      a2.y += wu * __uint_as_float(hv[u].z & 0xffff0000u);
      a3.x += wu * __uint_as_float(hv[u].w << 16);
      a3.y += wu * __uint_as_float(hv[u].w & 0xffff0000u);
    }
  }
  float inv = 1.0f / den;
  const float* bp = bias + 8 * l32;
  float4 bv0 = *(const float4*)(bp);
  float4 bv1 = *(const float4*)(bp + 4);
  float o0 = fmaxf(a0.x * inv + bv0.x, 0.f);
  float o1 = fmaxf(a0.y * inv + bv0.y, 0.f);
  float o2 = fmaxf(a1.x * inv + bv0.z, 0.f);
  float o3 = fmaxf(a1.y * inv + bv0.w, 0.f);
  float o4 = fmaxf(a2.x * inv + bv1.x, 0.f);
  float o5 = fmaxf(a2.y * inv + bv1.y, 0.f);
  float o6 = fmaxf(a3.x * inv + bv1.z, 0.f);
  float o7 = fmaxf(a3.y * inv + bv1.w, 0.f);
  uint4 o;
  o.x = (unsigned)f2bf(o0) | ((unsigned)f2bf(o1) << 16);
  o.y = (unsigned)f2bf(o2) | ((unsigned)f2bf(o3) << 16);
  o.z = (unsigned)f2bf(o4) | ((unsigned)f2bf(o5) << 16);
  o.w = (unsigned)f2bf(o6) | ((unsigned)f2bf(o7) << 16);
  *(uint4*)(hout + (size_t)n * WIDTH + 8 * l32) = o;
}

// ---------------- output head as MFMA GEMM ----------------
__global__ __launch_bounds__(256) void out_gemm_kernel(const unsigned short* __restrict__ h1,
                                                       const unsigned short* __restrict__ h2,
                                                       const unsigned short* __restrict__ h3,
                                                       const unsigned short* __restrict__ WoT,
                                                       const float* __restrict__ bo,
                                                       float* __restrict__ out){
  int tid = threadIdx.x, lane = tid & 63, wid = tid >> 6;
  int l15 = lane & 15, quad = lane >> 4;
  int m0 = blockIdx.x * 64 + 16 * wid;

  f32x4 acc[3];
  #pragma unroll
  for (int t = 0; t < 3; ++t) acc[t] = (f32x4){0.f, 0.f, 0.f, 0.f};

  int arow = m0 + l15; if (arow >= N_NODES) arow = N_NODES - 1;

  #pragma unroll
  for (int part = 0; part < 3; ++part){
    const unsigned short* hp = (part == 0) ? h1 : (part == 1) ? h2 : h3;
    const unsigned short* ap = hp + (size_t)arow * WIDTH;
    #pragma unroll
    for (int k0 = 0; k0 < WIDTH; k0 += 32){
      short8 af = *(const short8*)(ap + k0 + quad * 8);
      int kk = part * WIDTH + k0;
      #pragma unroll
      for (int t = 0; t < 3; ++t){
        short8 bf = *(const short8*)(WoT + (size_t)(16 * t + l15) * KCAT + kk + quad * 8);
        acc[t] = __builtin_amdgcn_mfma_f32_16x16x32_bf16(af, bf, acc[t], 0, 0, 0);
      }
    }
  }

  int r0 = m0 + quad * 4;
  #pragma unroll
  for (int t = 0; t < 3; ++t){
    int col = 16 * t + l15;
    if (col < NCLS){
      float bc = bo[col];
      #pragma unroll
      for (int r = 0; r < 4; ++r){
        int grow = r0 + r;
        if (grow < N_NODES) out[(size_t)grow * NCLS + col] = acc[t][r] + bc;
      }
    }
  }
}

// ---------------- host launch ----------------
static inline size_t align256(size_t x){ return (x + 255) & ~(size_t)255; }

extern "C" void kernel_launch(void* const* d_in, const int* in_sizes, int n_in,
                              void* d_out, int out_size, void* d_ws, size_t ws_size,
                              hipStream_t stream) {
  const float* x   = (const float*)d_in[0];
  const int*   ei  = (const int*)  d_in[1];
  const float* W1  = (const float*)d_in[2];
  const float* as1 = (const float*)d_in[3];
  const float* ad1 = (const float*)d_in[4];
  const float* b1  = (const float*)d_in[5];
  const float* W2  = (const float*)d_in[6];
  const float* as2 = (const float*)d_in[7];
  const float* ad2 = (const float*)d_in[8];
  const float* b2  = (const float*)d_in[9];
  const float* W3  = (const float*)d_in[10];
  const float* as3 = (const float*)d_in[11];
  const float* ad3 = (const float*)d_in[12];
  const float* b3  = (const float*)d_in[13];
  const float* Wo  = (const float*)d_in[14];
  const float* bo  = (const float*)d_in[15];
  float* out = (float*)d_out;

  char* p = (char*)d_ws;
  auto take = [&](size_t bytes) -> char* { char* cur = p; p += align256(bytes); return cur; };

  unsigned short* Wt1   = (unsigned short*)take((size_t)WIDTH * F_IN * 2);
  unsigned short* Wt2   = (unsigned short*)take((size_t)WIDTH * WIDTH * 2);
  unsigned short* Wt3   = (unsigned short*)take((size_t)WIDTH * WIDTH * 2);
  unsigned short* WoT   = (unsigned short*)take((size_t)NPAD * KCAT * 2);
  unsigned short* hstage= (unsigned short*)take((size_t)N_NODES * WIDTH * 2);
  float*          es    = (float*)take((size_t)N_NODES * 4 * 4);
  float*          ed    = (float*)take((size_t)N_NODES * 4 * 4);
  unsigned short* h1b   = (unsigned short*)take((size_t)N_NODES * WIDTH * 2);
  unsigned short* h2b   = (unsigned short*)take((size_t)N_NODES * WIDTH * 2);
  unsigned short* h3b   = (unsigned short*)take((size_t)N_NODES * WIDTH * 2);
  int*            counts  = (int*)take((size_t)N_NODES * 4);
  int*            offsets = (int*)take((size_t)(N_NODES + 1) * 4);
  int*            cursor  = (int*)take((size_t)N_NODES * 4);
  int*            srcs    = (int*)take((size_t)ETOT * 4);

  // prep: weight transposes
  transpose_w_kernel<<<dim3(F_IN / 256, WIDTH), 256, 0, stream>>>(W1, Wt1, F_IN, WIDTH);
  transpose_w_kernel<<<dim3(1, WIDTH), 256, 0, stream>>>(W2, Wt2, WIDTH, WIDTH);
  transpose_w_kernel<<<dim3(1, WIDTH), 256, 0, stream>>>(W3, Wt3, WIDTH, WIDTH);
  transpose_wo_kernel<<<(NPAD * KCAT + 255) / 256, 256, 0, stream>>>(Wo, WoT);

  // CSR build
  zero_kernel<<<(N_NODES + 255) / 256, 256, 0, stream>>>(counts, N_NODES);
  hist_kernel<<<(ETOT + 255) / 256, 256, 0, stream>>>(ei, counts);
  scan_kernel<<<1, 1024, 0, stream>>>(counts, offsets, cursor, N_NODES);
  scatter_kernel<<<(ETOT + 255) / 256, 256, 0, stream>>>(ei, cursor, srcs);

  const int gemm_grid = (N_NODES + BM - 1) / BM;   // 469
  const int agg_grid  = N_NODES / 8;               // 3750

  // layer 1 (A = x, f32, converted in staging)
  gemm_fused_kernel<true><<<gemm_grid, 256, 0, stream>>>(x, Wt1, as1, ad1, es, ed, hstage, N_NODES, F_IN);
  agg_kernel<<<agg_grid, 256, 0, stream>>>(offsets, srcs, es, ed, hstage, b1, h1b);
  // layer 2
  gemm_fused_kernel<false><<<gemm_grid, 256, 0, stream>>>(h1b, Wt2, as2, ad2, es, ed, hstage, N_NODES, WIDTH);
  agg_kernel<<<agg_grid, 256, 0, stream>>>(offsets, srcs, es, ed, hstage, b2, h2b);
  // layer 3
  gemm_fused_kernel<false><<<gemm_grid, 256, 0, stream>>>(h2b, Wt3, as3, ad3, es, ed, hstage, N_NODES, WIDTH);
  agg_kernel<<<agg_grid, 256, 0, stream>>>(offsets, srcs, es, ed, hstage, b3, h3b);

  // output head (MFMA GEMM)
  out_gemm_kernel<<<gemm_grid, 256, 0, stream>>>(h1b, h2b, h3b, WoT, bo, out);
}